// Round 3
// baseline (770.446 us; speedup 1.0000x reference)
//
#include <hip/hip_runtime.h>

// Quantized 2x conv via MFMA i8 (v_mfma_i32_16x16x64_i8), exact integer math.
// GEMM view: M=16 ow-pixels, N=16 cols (10 oc used), K=64 = kh(4, last zero)×c16.
// Activations NHWC-c16 so each lane's A-frag is one 16B contiguous load.
// A/B operand layouts are mirror-symmetric => our (group=kh, byte=c) k-order
// is valid as long as B is packed identically (prep does).
//
// ws layout:
//   [0,64)        consts: [0]=1/s_in [1]=si*sw1/so1 [2]=so1*sw2/so2 [3]=so2
//   [256,3328)    B1 frags: [kw][lane][4 dwords]  (3*64*4 ints)
//   [4096,7168)   B2 frags: same
//   [7424,7488)   bias1 (16 ints), [7680,7744) bias2 (16 ints)
//   [8192, +134217728)      XQ  [32][512][512][16] int8
//   [134225920, +133693440) YQ  [32][510][512][16] int8 (w padded to 512)

typedef int v4i __attribute__((ext_vector_type(4)));

#define XQ_OFF 8192ULL
#define YQ_OFF 134225920ULL

__device__ __forceinline__ float qclamp(float v) {
    return fminf(fmaxf(v, -128.0f), 127.0f);
}

__global__ __launch_bounds__(256) void prep_kernel(
    const float* __restrict__ w1, const float* __restrict__ b1,
    const float* __restrict__ w2, const float* __restrict__ b2,
    const float* __restrict__ s_in, const float* __restrict__ s_w1,
    const float* __restrict__ s_o1, const float* __restrict__ s_w2,
    const float* __restrict__ s_o2,
    float* __restrict__ consts, int* __restrict__ B1, int* __restrict__ B2,
    int* __restrict__ bias1, int* __restrict__ bias2)
{
    int t = threadIdx.x;
    float si = s_in[0], sw1 = s_w1[0], so1 = s_o1[0], sw2 = s_w2[0], so2 = s_o2[0];
    if (t == 0) {
        consts[0] = 1.0f / si;
        consts[1] = (si * sw1) / so1;   // 2^-7 exact
        consts[2] = (so1 * sw2) / so2;  // 2^-7 exact
        consts[3] = so2;
    }
    // B frag dword i = kw*256 + lane*4 + d ; lane: oc=lane&15, kh=lane>>4 ; byte j: c=d*4+j
    for (int i = t; i < 768; i += 256) {
        int kw = i >> 8, l = (i >> 2) & 63, d = i & 3;
        int oc = l & 15, kh = l >> 4;
        int val = 0;
        if (kh < 3 && oc < 10) {
            #pragma unroll
            for (int j = 0; j < 4; ++j) {
                int c = d * 4 + j;
                if (c < 5) {
                    int q = (int)qclamp(rintf(w1[((oc * 5 + c) * 3 + kh) * 3 + kw] / sw1));
                    val |= (q & 255) << (8 * j);
                }
            }
        }
        B1[i] = val;
    }
    for (int i = t; i < 768; i += 256) {
        int kw = i >> 8, l = (i >> 2) & 63, d = i & 3;
        int oc = l & 15, kh = l >> 4;
        int val = 0;
        if (kh < 3 && oc < 10) {
            #pragma unroll
            for (int j = 0; j < 4; ++j) {
                int c = d * 4 + j;
                if (c < 10) {
                    int q = (int)qclamp(rintf(w2[((oc * 10 + c) * 3 + kh) * 3 + kw] / sw2));
                    val |= (q & 255) << (8 * j);
                }
            }
        }
        B2[i] = val;
    }
    for (int i = t; i < 16; i += 256) {
        bias1[i] = (i < 10) ? (int)qclamp(rintf(b1[i] / (si * sw1))) : 0;
        bias2[i] = (i < 10) ? (int)qclamp(rintf(b2[i] / (so1 * sw2))) : 0;
    }
}

// x fp32 NCHW [32][5][512][512] -> XQ int8 NHWC-c16 [32][512][512][16]
__global__ __launch_bounds__(256) void quant_kernel(
    const float* __restrict__ x, const float* __restrict__ consts,
    signed char* __restrict__ xq)
{
    int nh = blockIdx.x;            // n*512 + h
    int n = nh >> 9, h = nh & 511;
    float inv = consts[0];
    const float* xb = x + (size_t)n * (5 * 262144) + (size_t)h * 512;
    signed char* ob = xq + ((size_t)nh * 512) * 16;
    for (int w = threadIdx.x; w < 512; w += 256) {
        int q0 = (int)qclamp(rintf(xb[0 * 262144 + w] * inv));
        int q1 = (int)qclamp(rintf(xb[1 * 262144 + w] * inv));
        int q2 = (int)qclamp(rintf(xb[2 * 262144 + w] * inv));
        int q3 = (int)qclamp(rintf(xb[3 * 262144 + w] * inv));
        int q4 = (int)qclamp(rintf(xb[4 * 262144 + w] * inv));
        v4i rec;
        rec[0] = (q0 & 255) | ((q1 & 255) << 8) | ((q2 & 255) << 16) | (q3 << 24);
        rec[1] = q4 & 255;
        rec[2] = 0;
        rec[3] = 0;
        *(v4i*)(ob + (size_t)w * 16) = rec;
    }
}

// conv1: XQ -> requant int8 -> YQ [32][510][512][16]
__global__ __launch_bounds__(256) void conv1_kernel(
    const signed char* __restrict__ XQ, const int* __restrict__ B1,
    const int* __restrict__ bias, const float* __restrict__ consts,
    signed char* __restrict__ YQ)
{
    int wv = (blockIdx.x * 256 + threadIdx.x) >> 6;
    int lane = threadIdx.x & 63;
    int owt = wv & 31, ohg = (wv >> 5) & 63, n = wv >> 11;
    int ow0 = owt << 4, oh0 = ohg << 3;
    int col = lane & 15;            // A: pixel m ; B/C: oc
    int g = lane >> 4;              // A: kh group ; C: pixel block
    v4i Bf0 = *(const v4i*)(B1 + (0 * 64 + lane) * 4);
    v4i Bf1 = *(const v4i*)(B1 + (1 * 64 + lane) * 4);
    v4i Bf2 = *(const v4i*)(B1 + (2 * 64 + lane) * 4);
    int bi = bias[col];
    float cr = consts[1];

    const signed char* abase =
        XQ + (((size_t)(n * 512 + oh0 + g) * 512) + (size_t)(ow0 + col)) * 16;

    for (int r = 0; r < 8; ++r) {
        int oh = oh0 + r;
        const signed char* ap = abase + (size_t)r * (512 * 16);
        v4i a0 = *(const v4i*)(ap);
        v4i a1 = *(const v4i*)(ap + 16);
        v4i a2 = *(const v4i*)(ap + 32);
        v4i acc = { bi, bi, bi, bi };
        acc = __builtin_amdgcn_mfma_i32_16x16x64_i8(a0, Bf0, acc, 0, 0, 0);
        acc = __builtin_amdgcn_mfma_i32_16x16x64_i8(a1, Bf1, acc, 0, 0, 0);
        acc = __builtin_amdgcn_mfma_i32_16x16x64_i8(a2, Bf2, acc, 0, 0, 0);
        if (col < 10 && oh < 510) {
            #pragma unroll
            for (int rr = 0; rr < 4; ++rr) {
                int ow = ow0 + g * 4 + rr;
                if (ow < 510) {
                    int q = (int)qclamp(rintf((float)acc[rr] * cr));
                    YQ[(((size_t)(n * 510 + oh) * 512) + ow) * 16 + col] = (signed char)q;
                }
            }
        }
    }
}

// conv2: YQ -> requant*so2 -> out fp32 NCHW [32][10][508][508]
__global__ __launch_bounds__(256) void conv2_kernel(
    const signed char* __restrict__ YQ, const int* __restrict__ B2,
    const int* __restrict__ bias, const float* __restrict__ consts,
    float* __restrict__ out)
{
    int wv = (blockIdx.x * 256 + threadIdx.x) >> 6;
    int lane = threadIdx.x & 63;
    int owt = wv & 31, ohg = (wv >> 5) & 63, n = wv >> 11;
    int ow0 = owt << 4, oh0 = ohg << 3;
    int col = lane & 15;
    int g = lane >> 4;
    v4i Bf0 = *(const v4i*)(B2 + (0 * 64 + lane) * 4);
    v4i Bf1 = *(const v4i*)(B2 + (1 * 64 + lane) * 4);
    v4i Bf2 = *(const v4i*)(B2 + (2 * 64 + lane) * 4);
    int bi = bias[col];
    float cr = consts[2], so = consts[3];

    const signed char* abase =
        YQ + (((size_t)(n * 510 + oh0 + g) * 512) + (size_t)(ow0 + col)) * 16;

    for (int r = 0; r < 8; ++r) {
        int oh = oh0 + r;
        const signed char* ap = abase + (size_t)r * (512 * 16);
        v4i a0 = *(const v4i*)(ap);
        v4i a1 = *(const v4i*)(ap + 16);
        v4i a2 = *(const v4i*)(ap + 32);
        v4i acc = { bi, bi, bi, bi };
        acc = __builtin_amdgcn_mfma_i32_16x16x64_i8(a0, Bf0, acc, 0, 0, 0);
        acc = __builtin_amdgcn_mfma_i32_16x16x64_i8(a1, Bf1, acc, 0, 0, 0);
        acc = __builtin_amdgcn_mfma_i32_16x16x64_i8(a2, Bf2, acc, 0, 0, 0);
        if (col < 10 && oh < 508) {
            #pragma unroll
            for (int rr = 0; rr < 4; ++rr) {
                int ow = ow0 + g * 4 + rr;
                if (ow < 508) {
                    out[(((size_t)(n * 10 + col) * 508) + oh) * 508 + ow] =
                        qclamp(rintf((float)acc[rr] * cr)) * so;
                }
            }
        }
    }
}

extern "C" void kernel_launch(void* const* d_in, const int* in_sizes, int n_in,
                              void* d_out, int out_size, void* d_ws, size_t ws_size,
                              hipStream_t stream) {
    const float* x    = (const float*)d_in[0];
    const float* w1   = (const float*)d_in[1];
    const float* b1   = (const float*)d_in[2];
    const float* w2   = (const float*)d_in[3];
    const float* b2   = (const float*)d_in[4];
    const float* s_in = (const float*)d_in[5];
    const float* s_w1 = (const float*)d_in[6];
    const float* s_o1 = (const float*)d_in[7];
    const float* s_w2 = (const float*)d_in[8];
    const float* s_o2 = (const float*)d_in[9];

    char* ws = (char*)d_ws;
    float* consts = (float*)ws;
    int* B1    = (int*)(ws + 256);
    int* B2    = (int*)(ws + 4096);
    int* bias1 = (int*)(ws + 7424);
    int* bias2 = (int*)(ws + 7680);
    signed char* XQ = (signed char*)(ws + XQ_OFF);
    signed char* YQ = (signed char*)(ws + YQ_OFF);

    prep_kernel<<<1, 256, 0, stream>>>(w1, b1, w2, b2, s_in, s_w1, s_o1, s_w2, s_o2,
                                       consts, B1, B2, bias1, bias2);

    // one block per (n,h) row
    quant_kernel<<<32 * 512, 256, 0, stream>>>(x, consts, XQ);

    // waves = 32n * 64 oh-groups * 32 ow-tiles = 65536 -> 16384 blocks
    conv1_kernel<<<16384, 256, 0, stream>>>(XQ, B1, bias1, consts, YQ);
    conv2_kernel<<<16384, 256, 0, stream>>>(YQ, B2, bias2, consts, (float*)d_out);
}

// Round 4
// 689.149 us; speedup vs baseline: 1.1180x; 1.1180x over previous
//
#include <hip/hip_runtime.h>

// Quantized 2x conv via MFMA i8, restructured for ILP + coalesced stores.
// conv1: A=weights(m=oc), B=activations(n=pixel) -> D row=oc,col=pixel:
//        lane packs 4 oc-bytes -> wave stores 256B contiguous c16 records.
// conv2: A=activations(m=pixel), B=weights(n=oc) -> D row=pixel,col=oc:
//        lane stores float4 (4 consecutive ow) per oc-plane.
// Both: 24 batched loads -> 24 MFMAs (8 independent acc chains) -> 1 epilogue.
// Exact integer math throughout (|acc| < 2^21, requant in fp32 is exact RNE).
//
// ws layout:
//   [0,64)        consts: [0]=1/s_in [1]=si*sw1/so1 [2]=so1*sw2/so2 [3]=so2
//   [256,3328)    B1 frags [kw][lane(kh*16+oc)][4 dwords(c)]
//   [4096,7168)   B2 frags same
//   [7424,7488)   bias1 (16 ints), [7680,7744) bias2 (16 ints)
//   [8192, +134217728)      XQ [32][512][512][16] int8
//   [134225920, +133693440) YQ [32][510][512][16] int8 (w padded to 512)
//   (+ ~32KB OOB-read slack after YQ; ws is ~1.3GB, reads stay in-buffer,
//    garbage contributes 0 via zero weights or discarded lanes)

typedef int v4i __attribute__((ext_vector_type(4)));

#define XQ_OFF 8192ULL
#define YQ_OFF 134225920ULL

__device__ __forceinline__ float qclamp(float v) {
    return fminf(fmaxf(v, -128.0f), 127.0f);
}

__global__ __launch_bounds__(256) void prep_kernel(
    const float* __restrict__ w1, const float* __restrict__ b1,
    const float* __restrict__ w2, const float* __restrict__ b2,
    const float* __restrict__ s_in, const float* __restrict__ s_w1,
    const float* __restrict__ s_o1, const float* __restrict__ s_w2,
    const float* __restrict__ s_o2,
    float* __restrict__ consts, int* __restrict__ B1, int* __restrict__ B2,
    int* __restrict__ bias1, int* __restrict__ bias2)
{
    int t = threadIdx.x;
    float si = s_in[0], sw1 = s_w1[0], so1 = s_o1[0], sw2 = s_w2[0], so2 = s_o2[0];
    if (t == 0) {
        consts[0] = 1.0f / si;
        consts[1] = (si * sw1) / so1;   // 2^-7 exact
        consts[2] = (so1 * sw2) / so2;  // 2^-7 exact
        consts[3] = so2;
    }
    // frag dword i = kw*256 + lane*4 + d ; lane: oc=lane&15, kh=lane>>4 ; byte j: c=4d+j
    for (int i = t; i < 768; i += 256) {
        int kw = i >> 8, l = (i >> 2) & 63, d = i & 3;
        int oc = l & 15, kh = l >> 4;
        int val = 0;
        if (kh < 3 && oc < 10) {
            #pragma unroll
            for (int j = 0; j < 4; ++j) {
                int c = d * 4 + j;
                if (c < 5) {
                    int q = (int)qclamp(rintf(w1[((oc * 5 + c) * 3 + kh) * 3 + kw] / sw1));
                    val |= (q & 255) << (8 * j);
                }
            }
        }
        B1[i] = val;
    }
    for (int i = t; i < 768; i += 256) {
        int kw = i >> 8, l = (i >> 2) & 63, d = i & 3;
        int oc = l & 15, kh = l >> 4;
        int val = 0;
        if (kh < 3 && oc < 10) {
            #pragma unroll
            for (int j = 0; j < 4; ++j) {
                int c = d * 4 + j;
                if (c < 10) {
                    int q = (int)qclamp(rintf(w2[((oc * 10 + c) * 3 + kh) * 3 + kw] / sw2));
                    val |= (q & 255) << (8 * j);
                }
            }
        }
        B2[i] = val;
    }
    for (int i = t; i < 16; i += 256) {
        bias1[i] = (i < 10) ? (int)qclamp(rintf(b1[i] / (si * sw1))) : 0;
        bias2[i] = (i < 10) ? (int)qclamp(rintf(b2[i] / (so1 * sw2))) : 0;
    }
}

// x fp32 NCHW [32][5][512][512] -> XQ int8 NHWC-c16 [32][512][512][16]
__global__ __launch_bounds__(256) void quant_kernel(
    const float* __restrict__ x, const float* __restrict__ consts,
    signed char* __restrict__ xq)
{
    int nh = blockIdx.x;            // n*512 + h
    int n = nh >> 9, h = nh & 511;
    float inv = consts[0];
    const float* xb = x + (size_t)n * (5 * 262144) + (size_t)h * 512;
    signed char* ob = xq + ((size_t)nh * 512) * 16;
    for (int w = threadIdx.x; w < 512; w += 256) {
        int q0 = (int)qclamp(rintf(xb[0 * 262144 + w] * inv));
        int q1 = (int)qclamp(rintf(xb[1 * 262144 + w] * inv));
        int q2 = (int)qclamp(rintf(xb[2 * 262144 + w] * inv));
        int q3 = (int)qclamp(rintf(xb[3 * 262144 + w] * inv));
        int q4 = (int)qclamp(rintf(xb[4 * 262144 + w] * inv));
        v4i rec;
        rec[0] = (q0 & 255) | ((q1 & 255) << 8) | ((q2 & 255) << 16) | (q3 << 24);
        rec[1] = q4 & 255;
        rec[2] = 0;
        rec[3] = 0;
        *(v4i*)(ob + (size_t)w * 16) = rec;
    }
}

// conv1: XQ -> requant -> YQ [32][510][512][16]. A=weights, B=activations.
__global__ __launch_bounds__(256) void conv1_kernel(
    const signed char* __restrict__ XQ, const int* __restrict__ B1,
    const int* __restrict__ bias, const float* __restrict__ consts,
    signed char* __restrict__ YQ)
{
    int wv = (blockIdx.x * 256 + threadIdx.x) >> 6;
    int lane = threadIdx.x & 63;
    int owt = wv & 31, ohb = (wv >> 5) & 63, n = wv >> 11;
    int ow0 = owt << 4, oh0 = ohb << 3;
    int p = lane & 15;              // A:m=oc ; B:n=pixel ; D:col=pixel
    int q = lane >> 4;              // k-group = kh ; D row group

    v4i A0 = *(const v4i*)(B1 + (0 * 64 + lane) * 4);
    v4i A1 = *(const v4i*)(B1 + (1 * 64 + lane) * 4);
    v4i A2 = *(const v4i*)(B1 + (2 * 64 + lane) * 4);
    v4i binit = *(const v4i*)(bias + q * 4);     // acc rr -> oc = q*4+rr

    const signed char* base =
        XQ + (((size_t)(n * 512 + oh0 + q) * 512) + (size_t)(ow0 + p)) * 16;

    v4i L[8][3];
    #pragma unroll
    for (int r = 0; r < 8; ++r) {
        const signed char* pr = base + (size_t)r * 8192;
        L[r][0] = *(const v4i*)(pr);
        L[r][1] = *(const v4i*)(pr + 16);
        L[r][2] = *(const v4i*)(pr + 32);
    }
    v4i acc[8];
    #pragma unroll
    for (int r = 0; r < 8; ++r) {
        v4i a = __builtin_amdgcn_mfma_i32_16x16x64_i8(A0, L[r][0], binit, 0, 0, 0);
        a     = __builtin_amdgcn_mfma_i32_16x16x64_i8(A1, L[r][1], a,     0, 0, 0);
        acc[r]= __builtin_amdgcn_mfma_i32_16x16x64_i8(A2, L[r][2], a,     0, 0, 0);
    }

    float cr = consts[1];
    signed char* obase = YQ + (((size_t)(n * 510 + oh0) * 512) + (size_t)(ow0 + p)) * 16 + q * 4;
    #pragma unroll
    for (int r = 0; r < 8; ++r) {
        if (oh0 + r < 510) {
            int q0 = (int)qclamp(rintf((float)acc[r][0] * cr));
            int q1 = (int)qclamp(rintf((float)acc[r][1] * cr));
            int q2 = (int)qclamp(rintf((float)acc[r][2] * cr));
            int q3 = (int)qclamp(rintf((float)acc[r][3] * cr));
            *(int*)(obase + (size_t)r * 8192) =
                (q0 & 255) | ((q1 & 255) << 8) | ((q2 & 255) << 16) | (q3 << 24);
        }
    }
}

// conv2: YQ -> requant*so2 -> out fp32 NCHW. A=activations, B=weights.
__global__ __launch_bounds__(256) void conv2_kernel(
    const signed char* __restrict__ YQ, const int* __restrict__ B2,
    const int* __restrict__ bias, const float* __restrict__ consts,
    float* __restrict__ out)
{
    int wv = (blockIdx.x * 256 + threadIdx.x) >> 6;
    int lane = threadIdx.x & 63;
    int owt = wv & 31, ohb = (wv >> 5) & 63, n = wv >> 11;
    int ow0 = owt << 4, oh0 = ohb << 3;
    int p = lane & 15;              // A:m=pixel ; B:n=oc ; D:col=oc
    int q = lane >> 4;              // k-group = kh ; D row group (pixel)

    v4i W0 = *(const v4i*)(B2 + (0 * 64 + lane) * 4);
    v4i W1 = *(const v4i*)(B2 + (1 * 64 + lane) * 4);
    v4i W2 = *(const v4i*)(B2 + (2 * 64 + lane) * 4);
    int bi = bias[p];
    v4i binit = { bi, bi, bi, bi };

    const signed char* base =
        YQ + (((size_t)(n * 510 + oh0 + q) * 512) + (size_t)(ow0 + p)) * 16;

    v4i L[8][3];
    #pragma unroll
    for (int r = 0; r < 8; ++r) {
        const signed char* pr = base + (size_t)r * 8192;
        L[r][0] = *(const v4i*)(pr);
        L[r][1] = *(const v4i*)(pr + 16);
        L[r][2] = *(const v4i*)(pr + 32);
    }
    v4i acc[8];
    #pragma unroll
    for (int r = 0; r < 8; ++r) {
        v4i a = __builtin_amdgcn_mfma_i32_16x16x64_i8(L[r][0], W0, binit, 0, 0, 0);
        a     = __builtin_amdgcn_mfma_i32_16x16x64_i8(L[r][1], W1, a,     0, 0, 0);
        acc[r]= __builtin_amdgcn_mfma_i32_16x16x64_i8(L[r][2], W2, a,     0, 0, 0);
    }

    float cr = consts[2], so = consts[3];
    int ow_base = ow0 + q * 4;
    bool owok = (ow_base + 3) < 508;             // 508 % 4 == 0: all-or-none
    #pragma unroll
    for (int r = 0; r < 8; ++r) {
        int oh = oh0 + r;
        if (p < 10 && owok && oh < 508) {
            float4 v;
            v.x = qclamp(rintf((float)acc[r][0] * cr)) * so;
            v.y = qclamp(rintf((float)acc[r][1] * cr)) * so;
            v.z = qclamp(rintf((float)acc[r][2] * cr)) * so;
            v.w = qclamp(rintf((float)acc[r][3] * cr)) * so;
            *(float4*)(out + (((size_t)(n * 10 + p) * 508) + oh) * 508 + ow_base) = v;
        }
    }
}

extern "C" void kernel_launch(void* const* d_in, const int* in_sizes, int n_in,
                              void* d_out, int out_size, void* d_ws, size_t ws_size,
                              hipStream_t stream) {
    const float* x    = (const float*)d_in[0];
    const float* w1   = (const float*)d_in[1];
    const float* b1   = (const float*)d_in[2];
    const float* w2   = (const float*)d_in[3];
    const float* b2   = (const float*)d_in[4];
    const float* s_in = (const float*)d_in[5];
    const float* s_w1 = (const float*)d_in[6];
    const float* s_o1 = (const float*)d_in[7];
    const float* s_w2 = (const float*)d_in[8];
    const float* s_o2 = (const float*)d_in[9];

    char* ws = (char*)d_ws;
    float* consts = (float*)ws;
    int* B1    = (int*)(ws + 256);
    int* B2    = (int*)(ws + 4096);
    int* bias1 = (int*)(ws + 7424);
    int* bias2 = (int*)(ws + 7680);
    signed char* XQ = (signed char*)(ws + XQ_OFF);
    signed char* YQ = (signed char*)(ws + YQ_OFF);

    prep_kernel<<<1, 256, 0, stream>>>(w1, b1, w2, b2, s_in, s_w1, s_o1, s_w2, s_o2,
                                       consts, B1, B2, bias1, bias2);

    quant_kernel<<<32 * 512, 256, 0, stream>>>(x, consts, XQ);

    // waves = 32n * 64 oh-blocks * 32 ow-tiles = 65536 -> 16384 blocks
    conv1_kernel<<<16384, 256, 0, stream>>>(XQ, B1, bias1, consts, YQ);
    conv2_kernel<<<16384, 256, 0, stream>>>(YQ, B2, bias2, consts, (float*)d_out);
}